// Round 1
// baseline (613.045 us; speedup 1.0000x reference)
//
#include <hip/hip_runtime.h>
#include <hip/hip_bf16.h>
#include <stdint.h>

// ---------------------------------------------------------------------------
// Fused readout: gate = sigmoid(MLP_g([h0;hT])), val = MLP_o(hT),
// out[b,:] = sum_n mask(b,n) * gate * val.
// B=512, N=256, rows = 131072. One WG = 256 threads (4 waves) = 64 rows.
// All matmuls bf16 MFMA 16x16x32, fp32 accum. Weights pre-swizzled bf16 in ws.
// ---------------------------------------------------------------------------

typedef __attribute__((ext_vector_type(8))) short short8_t;
typedef __attribute__((ext_vector_type(4))) float f32x4;

// LDS layout (bytes)
#define OFF_XV    0        // X [64][520] bf16 (66560 B); later val1 [64][264], val2 [64][264]
#define OFF_ACTA  67584    // actA [64][136] bf16 (17408 B)
#define OFF_ACTB  84992    // actB [64][264] bf16 (33792 B)
#define OFF_WLDS  118784   // weight chunk [N][64] bf16, max 32768 B
#define OFF_MASK  151552   // 64 floats
#define LDS_TOTAL 151808

__device__ __forceinline__ short f2bf(float f) {
  union { float f; uint32_t u; } v; v.f = f;
  uint32_t r = (v.u + 0x7FFFu + ((v.u >> 16) & 1u)) >> 16;  // RNE
  return (short)r;
}
__device__ __forceinline__ float bf2f(short b) {
  union { uint32_t u; float f; } v; v.u = ((uint32_t)(uint16_t)b) << 16;
  return v.f;
}

__device__ __forceinline__ void load_lds16(const void* g, void* l) {
  __builtin_amdgcn_global_load_lds((const __attribute__((address_space(1))) uint32_t*)g,
                                   (__attribute__((address_space(3))) uint32_t*)l, 16, 0, 0);
}

// One MLP layer: act_in [64][K] (LDS, stride Sin) @ W [K][N] + bias -> act_out [64][N]
// ACTF: 0 = none, 1 = relu, 2 = sigmoid. Weights from ws (bf16, chunk-swizzled).
template <int K, int N, int ACTF>
__device__ __forceinline__ void layer(const short* actin, int Sin,
                                      short* actout, int Sout,
                                      const short* wsW, const float* bias,
                                      short* Wlds, int tid) {
  constexpr int CT = N / 64;              // col-tiles per wave (2 or 4)
  const int wv = tid >> 6, lane = tid & 63;
  const int m = lane & 15, q = lane >> 4;

  f32x4 acc[4][CT];
#pragma unroll
  for (int rt = 0; rt < 4; ++rt)
#pragma unroll
    for (int ct = 0; ct < CT; ++ct) acc[rt][ct] = (f32x4)(0.f);

  constexpr int NCHUNK = K / 64;
  constexpr int SITER = (N * 128) / 4096;  // wave-iterations of 1024 B each
  for (int kc = 0; kc < NCHUNK; ++kc) {
    __syncthreads();  // all waves done reading previous Wlds chunk / prev layer
    const char* src = (const char*)(wsW + kc * (N * 64));
#pragma unroll
    for (int i = 0; i < SITER; ++i) {
      const int off = (i * 4 + wv) * 1024;
      load_lds16(src + off + lane * 16, (char*)Wlds + off);
    }
    __syncthreads();  // compiler drains vmcnt before barrier
#pragma unroll
    for (int ks = 0; ks < 2; ++ks) {
      const int k = kc * 64 + ks * 32;
      short8_t a[4];
#pragma unroll
      for (int rt = 0; rt < 4; ++rt)
        a[rt] = *(const short8_t*)(actin + (rt * 16 + m) * Sin + k + q * 8);
#pragma unroll
      for (int ct = 0; ct < CT; ++ct) {
        const int n = wv * (CT * 16) + ct * 16 + m;
        const int phys = (ks * 4 + q) ^ (n & 7);  // undo staging swizzle
        const short8_t b = *(const short8_t*)(Wlds + n * 64 + phys * 8);
#pragma unroll
        for (int rt = 0; rt < 4; ++rt)
          acc[rt][ct] = __builtin_amdgcn_mfma_f32_16x16x32_bf16(a[rt], b, acc[rt][ct], 0, 0, 0);
      }
    }
  }
  // epilogue: bias + activation, write bf16. C/D: col=lane&15, row=quad*4+i.
#pragma unroll
  for (int ct = 0; ct < CT; ++ct) {
    const int col = wv * (CT * 16) + ct * 16 + m;
    const float bv = bias[col];
#pragma unroll
    for (int rt = 0; rt < 4; ++rt) {
#pragma unroll
      for (int i = 0; i < 4; ++i) {
        float v = acc[rt][ct][i] + bv;
        if (ACTF == 1) v = fmaxf(v, 0.f);
        if (ACTF == 2) v = 1.f / (1.f + __expf(-v));
        actout[(rt * 16 + q * 4 + i) * Sout + col] = f2bf(v);
      }
    }
  }
}

__global__ __launch_bounds__(256, 1)
void readout_main(const float* __restrict__ h0, const float* __restrict__ hT,
                  const short* __restrict__ ws,
                  const float* __restrict__ gb0, const float* __restrict__ gb1,
                  const float* __restrict__ gb2, const float* __restrict__ gb3,
                  const float* __restrict__ ob0, const float* __restrict__ ob1,
                  const float* __restrict__ ob2, const float* __restrict__ ob3,
                  float* __restrict__ out) {
  __shared__ __align__(16) char smem[LDS_TOTAL];
  short* X    = (short*)(smem + OFF_XV);                  // [64][520]
  short* val1 = (short*)(smem + OFF_XV);                  // [64][264] (X dead by then)
  short* val2 = (short*)(smem + OFF_XV + 64 * 264 * 2);   // [64][264]
  short* actA = (short*)(smem + OFF_ACTA);                // [64][136]
  short* actB = (short*)(smem + OFF_ACTB);                // [64][264]
  short* Wlds = (short*)(smem + OFF_WLDS);
  float* maskL = (float*)(smem + OFF_MASK);

  const int tid = threadIdx.x;
  const int wv = tid >> 6, lane = tid & 63;
  const int wg = blockIdx.x;
  const long long row0 = (long long)wg * 64;

  // ---- stage inputs: X = [bf16(h0) | bf16(hT)], mask from fp32 h0 row-sum ----
  for (int i = 0; i < 16; ++i) {
    const int lr = i * 4 + wv;
    const float* p0 = h0 + (row0 + lr) * 256;
    const float4 v = *(const float4*)(p0 + lane * 4);
    float s = v.x + v.y + v.z + v.w;
#pragma unroll
    for (int off = 32; off > 0; off >>= 1) s += __shfl_down(s, off);
    if (lane == 0) maskL[lr] = (s > 0.f) ? 1.f : 0.f;
    short4 pk; pk.x = f2bf(v.x); pk.y = f2bf(v.y); pk.z = f2bf(v.z); pk.w = f2bf(v.w);
    *(short4*)(X + lr * 520 + lane * 4) = pk;
    const float* p1 = hT + (row0 + lr) * 256;
    const float4 u = *(const float4*)(p1 + lane * 4);
    short4 pk2; pk2.x = f2bf(u.x); pk2.y = f2bf(u.y); pk2.z = f2bf(u.z); pk2.w = f2bf(u.w);
    *(short4*)(X + lr * 520 + 256 + lane * 4) = pk2;
  }
  // (layer() starts with __syncthreads())

  // gate chain
  layer<512, 128, 1>(X,        520, actA, 136, ws + 0,      gb0, Wlds, tid);
  layer<128, 256, 1>(actA,     136, actB, 264, ws + 65536,  gb1, Wlds, tid);
  layer<256, 128, 1>(actB,     264, actA, 136, ws + 98304,  gb2, Wlds, tid);
  layer<128, 256, 2>(actA,     136, actB, 264, ws + 131072, gb3, Wlds, tid);  // gate in actB
  // value chain (v0 reads hT half of X; X region then recycled as val1/val2)
  layer<256, 128, 1>(X + 256,  520, actA, 136, ws + 163840, ob0, Wlds, tid);
  layer<128, 256, 1>(actA,     136, val1, 264, ws + 196608, ob1, Wlds, tid);
  layer<256, 128, 1>(val1,     264, actA, 136, ws + 229376, ob2, Wlds, tid);
  layer<128, 256, 0>(actA,     136, val2, 264, ws + 262144, ob3, Wlds, tid);  // val in val2

  __syncthreads();
  // ---- reduce over 64 rows: thread = column ----
  float s = 0.f;
#pragma unroll 4
  for (int lr = 0; lr < 64; ++lr) {
    const float g = bf2f(actB[lr * 264 + tid]);
    const float v = bf2f(val2[lr * 264 + tid]);
    s += maskL[lr] * g * v;
  }
  atomicAdd(out + (wg >> 2) * 256 + tid, s);
}

// Pre-pass: zero d_out; convert W fp32 -> bf16 into ws with the chunk-swizzled
// layout: ws[((kc*N + n)*8 + p)*8 + j] = bf16(W[kc*64 + (p^(n&7))*8 + j][n]).
__global__ void prep(const float* __restrict__ W0, const float* __restrict__ W1,
                     const float* __restrict__ W2, const float* __restrict__ W3,
                     const float* __restrict__ W4, const float* __restrict__ W5,
                     const float* __restrict__ W6, const float* __restrict__ W7,
                     short* __restrict__ ws, float* __restrict__ out) {
  const int e = blockIdx.x * 256 + threadIdx.x;  // < 294912
  if (e < 131072) out[e] = 0.f;
  const int offs[9] = {0, 65536, 98304, 131072, 163840, 196608, 229376, 262144, 294912};
  int l = 0;
  while (e >= offs[l + 1]) ++l;
  const int le = e - offs[l];
  const int N = (l & 1) ? 256 : 128;      // layers alternate N: 128,256,128,256,...
  const int j = le & 7, p = (le >> 3) & 7;
  const int n = (le >> 6) & (N - 1);
  const int kc = le >> (6 + ((N == 256) ? 8 : 7));
  const int k = kc * 64 + ((p ^ (n & 7)) << 3) + j;
  const float* W = (l == 0) ? W0 : (l == 1) ? W1 : (l == 2) ? W2 : (l == 3) ? W3
                 : (l == 4) ? W4 : (l == 5) ? W5 : (l == 6) ? W6 : W7;
  ws[e] = f2bf(W[k * N + n]);
}

extern "C" void kernel_launch(void* const* d_in, const int* in_sizes, int n_in,
                              void* d_out, int out_size, void* d_ws, size_t ws_size,
                              hipStream_t stream) {
  const float* h0  = (const float*)d_in[0];
  const float* hT  = (const float*)d_in[1];
  const float* gW0 = (const float*)d_in[2];  const float* gb0 = (const float*)d_in[3];
  const float* gW1 = (const float*)d_in[4];  const float* gb1 = (const float*)d_in[5];
  const float* gW2 = (const float*)d_in[6];  const float* gb2 = (const float*)d_in[7];
  const float* gW3 = (const float*)d_in[8];  const float* gb3 = (const float*)d_in[9];
  const float* oW0 = (const float*)d_in[10]; const float* ob0 = (const float*)d_in[11];
  const float* oW1 = (const float*)d_in[12]; const float* ob1 = (const float*)d_in[13];
  const float* oW2 = (const float*)d_in[14]; const float* ob2 = (const float*)d_in[15];
  const float* oW3 = (const float*)d_in[16]; const float* ob3 = (const float*)d_in[17];
  float* out = (float*)d_out;
  short* ws  = (short*)d_ws;  // needs 589824 B

  prep<<<1152, 256, 0, stream>>>(gW0, gW1, gW2, gW3, oW0, oW1, oW2, oW3, ws, out);
  readout_main<<<2048, 256, 0, stream>>>(h0, hT, ws,
                                         gb0, gb1, gb2, gb3,
                                         ob0, ob1, ob2, ob3, out);
}

// Round 2
// 520.753 us; speedup vs baseline: 1.1772x; 1.1772x over previous
//
#include <hip/hip_runtime.h>
#include <hip/hip_bf16.h>
#include <stdint.h>

// ---------------------------------------------------------------------------
// Round 2: no weight-LDS staging. B-fragments load directly global->VGPR from
// pre-transposed bf16 W^T[n][k] (L2-resident, 576 KB total). 48 rows/WG,
// 256 threads (4 waves), LDS 62 KB -> 2 blocks/CU. Input streamed through a
// double-buffered 128-col chunk. Final reduce fused into last layer epilogue.
// ---------------------------------------------------------------------------

typedef __attribute__((ext_vector_type(8))) short short8_t;
typedef __attribute__((ext_vector_type(4))) float f32x4;

#define ROWS      48
#define TOTROWS   131072
#define NWG       2731          // ceil(131072/48)

// LDS layout (bytes)
#define OFF_R     0             // P db: 2 x [48][136] (26112) ; aliased: B2 [48][264] (25344)
#define P_ELEMS   (48*136)      // 6528 shorts per buffer
#define OFF_A     26112         // A [48][136] = 13056
#define OFF_B1    39168         // gate [48][256] = 24576
#define OFF_MASK  63744         // 48 floats
#define LDS_TOTAL 63936

__device__ __forceinline__ short f2bf(float f) {
  union { float f; uint32_t u; } v; v.f = f;
  uint32_t r = (v.u + 0x7FFFu + ((v.u >> 16) & 1u)) >> 16;  // RNE
  return (short)r;
}
__device__ __forceinline__ float bf2f(short b) {
  union { uint32_t u; float f; } v; v.u = ((uint32_t)(uint16_t)b) << 16;
  return v.f;
}

// ---- generic MFMA block: A from LDS (local k), B straight from global ------
// KTOT = weight k-stride; kbaseB = k offset into weights for this chunk.
template <int KTOT, int KSTEPS, int CT>
__device__ __forceinline__ void gemm_block(const short* __restrict__ actin, int Sin,
                                           const short* __restrict__ wsB, int kbaseB,
                                           f32x4 (&acc)[3][CT], int wv, int m, int q) {
#pragma unroll
  for (int ks = 0; ks < KSTEPS; ++ks) {
    const int kl = ks * 32 + q * 8;          // local k in act chunk
    short8_t b[CT];
#pragma unroll
    for (int ct = 0; ct < CT; ++ct) {
      const int n = wv * (CT * 16) + ct * 16 + m;
      b[ct] = *(const short8_t*)(wsB + n * KTOT + kbaseB + kl);
    }
    short8_t a[3];
#pragma unroll
    for (int rt = 0; rt < 3; ++rt)
      a[rt] = *(const short8_t*)(actin + (rt * 16 + m) * Sin + kl);
#pragma unroll
    for (int ct = 0; ct < CT; ++ct)
#pragma unroll
      for (int rt = 0; rt < 3; ++rt)
        acc[rt][ct] = __builtin_amdgcn_mfma_f32_16x16x32_bf16(a[rt], b[ct], acc[rt][ct], 0, 0, 0);
  }
}

// ---- epilogue: bias + activation -> bf16 LDS. C/D: col=lane&15, row=q*4+i --
template <int N, int ACTF>
__device__ __forceinline__ void epilogue(f32x4 (&acc)[3][N / 64], short* actout, int Sout,
                                         const float* __restrict__ bias, int wv, int m, int q) {
  constexpr int CT = N / 64;
#pragma unroll
  for (int ct = 0; ct < CT; ++ct) {
    const int c = wv * (CT * 16) + ct * 16 + m;
    const float bv = bias[c];
#pragma unroll
    for (int rt = 0; rt < 3; ++rt)
#pragma unroll
      for (int i = 0; i < 4; ++i) {
        float v = acc[rt][ct][i] + bv;
        if (ACTF == 1) v = fmaxf(v, 0.f);
        if (ACTF == 2) v = 1.f / (1.f + __expf(-v));
        actout[(rt * 16 + q * 4 + i) * Sout + c] = f2bf(v);
      }
  }
}

template <int K, int N, int ACTF>
__device__ __forceinline__ void layer(const short* actin, int Sin, short* actout, int Sout,
                                      const short* __restrict__ wsB, const float* __restrict__ bias,
                                      int wv, int m, int q) {
  constexpr int CT = N / 64;
  f32x4 acc[3][CT];
#pragma unroll
  for (int rt = 0; rt < 3; ++rt)
#pragma unroll
    for (int ct = 0; ct < CT; ++ct) acc[rt][ct] = (f32x4)(0.f);
  gemm_block<K, K / 32, CT>(actin, Sin, wsB, 0, acc, wv, m, q);
  epilogue<N, ACTF>(acc, actout, Sout, bias, wv, m, q);
}

// ---- input streaming: 48 rows x 128 cols fp32 per chunk --------------------
__device__ __forceinline__ void stage_load(const float* __restrict__ src, int row0, int colbase,
                                           int tid, float4 (&v)[6]) {
  const int c4 = tid & 31, rb = tid >> 5;
#pragma unroll
  for (int it = 0; it < 6; ++it) {
    int gr = row0 + rb + it * 8;
    if (gr >= TOTROWS) gr = TOTROWS - 1;
    v[it] = *(const float4*)(src + (size_t)gr * 256 + colbase + c4 * 4);
  }
}

// mmode: 0 none, 1 init maskacc, 2 accumulate maskacc
__device__ __forceinline__ void stage_store(short* Pb, int tid, const float4 (&v)[6],
                                            float* maskacc, int mmode) {
  const int c4 = tid & 31, rb = tid >> 5;
#pragma unroll
  for (int it = 0; it < 6; ++it) {
    const int r = rb + it * 8;
    short4 pk; pk.x = f2bf(v[it].x); pk.y = f2bf(v[it].y); pk.z = f2bf(v[it].z); pk.w = f2bf(v[it].w);
    *(short4*)(Pb + r * 136 + c4 * 4) = pk;
    if (mmode) {
      float s = v[it].x + v[it].y + v[it].z + v[it].w;
      s += __shfl_down(s, 16, 32);
      s += __shfl_down(s, 8, 32);
      s += __shfl_down(s, 4, 32);
      s += __shfl_down(s, 2, 32);
      s += __shfl_down(s, 1, 32);
      if (c4 == 0) {
        if (mmode == 1) maskacc[r] = s; else maskacc[r] += s;
      }
    }
  }
}

// Streamed first layer: input from global (chunk kc < splitc -> src0, else src1),
// double-buffered P; N=128 output -> Aout with ReLU.
template <int NCH, bool MASKA>
__device__ __forceinline__ void stream_layer(const float* __restrict__ src0,
                                             const float* __restrict__ src1, int splitc,
                                             const short* __restrict__ wsB,
                                             const float* __restrict__ bias,
                                             short* P, short* Aout, float* maskacc,
                                             int row0, int tid, int wv, int m, int q) {
  constexpr int KTOT = NCH * 128;
  f32x4 acc[3][2];
#pragma unroll
  for (int rt = 0; rt < 3; ++rt)
#pragma unroll
    for (int ct = 0; ct < 2; ++ct) acc[rt][ct] = (f32x4)(0.f);

  float4 v[6];
  stage_load(src0, row0, 0, tid, v);
  stage_store(P, tid, v, maskacc, MASKA ? 1 : 0);
  __syncthreads();
#pragma unroll
  for (int kc = 0; kc < NCH; ++kc) {
    const bool more = (kc + 1 < NCH);
    if (more) {
      const bool lo = (kc + 1 < splitc);
      stage_load(lo ? src0 : src1, row0, (lo ? (kc + 1) : (kc + 1 - splitc)) * 128, tid, v);
    }
    gemm_block<KTOT, 4, 2>(P + (kc & 1) * P_ELEMS, 136, wsB, kc * 128, acc, wv, m, q);
    if (more) {
      const int mm = (MASKA && (kc + 1 < splitc)) ? 2 : 0;
      stage_store(P + ((kc + 1) & 1) * P_ELEMS, tid, v, maskacc, mm);
    }
    __syncthreads();
  }
  epilogue<128, 1>(acc, Aout, 136, bias, wv, m, q);
}

// Last layer (o3): K=128 N=256, fused mask*gate*val reduce + atomicAdd.
__device__ __forceinline__ void final_layer(const short* actin, const short* __restrict__ wsB,
                                            const float* __restrict__ bias,
                                            const short* gateB, const float* maskacc,
                                            float* __restrict__ out, int row0,
                                            int wv, int m, int q) {
  f32x4 acc[3][4];
#pragma unroll
  for (int rt = 0; rt < 3; ++rt)
#pragma unroll
    for (int ct = 0; ct < 4; ++ct) acc[rt][ct] = (f32x4)(0.f);
  gemm_block<128, 4, 4>(actin, 136, wsB, 0, acc, wv, m, q);

  const int b0 = row0 >> 8;
  const int b1 = (row0 + ROWS - 1) >> 8;
#pragma unroll
  for (int ct = 0; ct < 4; ++ct) {
    const int c = wv * 64 + ct * 16 + m;
    const float bv = bias[c];
    float p0 = 0.f, p1 = 0.f;
#pragma unroll
    for (int rt = 0; rt < 3; ++rt)
#pragma unroll
      for (int i = 0; i < 4; ++i) {
        const int r = rt * 16 + q * 4 + i;
        const int gr = row0 + r;
        const float vv = acc[rt][ct][i] + bv;
        const float g = bf2f(gateB[r * 256 + c]);
        float contrib = (gr < TOTROWS && maskacc[r] > 0.f) ? g * vv : 0.f;
        if ((gr >> 8) == b0) p0 += contrib; else p1 += contrib;
      }
    p0 += __shfl_down(p0, 32); p0 += __shfl_down(p0, 16);
    p1 += __shfl_down(p1, 32); p1 += __shfl_down(p1, 16);
    if (q == 0) {
      atomicAdd(out + b0 * 256 + c, p0);
      if (b1 != b0 && b1 < 512) atomicAdd(out + b1 * 256 + c, p1);
    }
  }
}

__global__ __launch_bounds__(256, 2)
void readout_main(const float* __restrict__ h0, const float* __restrict__ hT,
                  const short* __restrict__ ws,
                  const float* __restrict__ gb0, const float* __restrict__ gb1,
                  const float* __restrict__ gb2, const float* __restrict__ gb3,
                  const float* __restrict__ ob0, const float* __restrict__ ob1,
                  const float* __restrict__ ob2, const float* __restrict__ ob3,
                  float* __restrict__ out) {
  __shared__ __align__(16) char smem[LDS_TOTAL];
  short* P  = (short*)(smem + OFF_R);           // db stage; aliases B2 (disjoint lifetimes)
  short* B2 = (short*)(smem + OFF_R);           // [48][264]
  short* A  = (short*)(smem + OFF_A);           // [48][136]
  short* B1 = (short*)(smem + OFF_B1);          // gate [48][256]
  float* maskacc = (float*)(smem + OFF_MASK);

  const int tid = threadIdx.x;
  const int wv = tid >> 6, lane = tid & 63;
  const int m = lane & 15, q = lane >> 4;
  const int row0 = blockIdx.x * ROWS;

  // gate chain
  stream_layer<4, true>(h0, hT, 2, ws + 0, gb0, P, A, maskacc, row0, tid, wv, m, q);
  __syncthreads();
  layer<128, 256, 1>(A, 136, B2, 264, ws + 65536, gb1, wv, m, q);
  __syncthreads();
  layer<256, 128, 1>(B2, 264, A, 136, ws + 98304, gb2, wv, m, q);
  __syncthreads();
  layer<128, 256, 2>(A, 136, B1, 256, ws + 131072, gb3, wv, m, q);   // sigmoid -> gate
  __syncthreads();
  // value chain (hT re-streamed; L2-warm)
  stream_layer<2, false>(hT, hT, 2, ws + 163840, ob0, P, A, maskacc, row0, tid, wv, m, q);
  __syncthreads();
  layer<128, 256, 1>(A, 136, B2, 264, ws + 196608, ob1, wv, m, q);
  __syncthreads();
  layer<256, 128, 1>(B2, 264, A, 136, ws + 229376, ob2, wv, m, q);
  __syncthreads();
  final_layer(A, ws + 262144, ob3, B1, maskacc, out, row0, wv, m, q);
}

// ---- prep: transpose weights fp32[K][N] -> bf16 W^T[n][K]; zero out --------
__global__ void prep(const float* __restrict__ W0, const float* __restrict__ W1,
                     const float* __restrict__ W2, const float* __restrict__ W3,
                     const float* __restrict__ W4, const float* __restrict__ W5,
                     const float* __restrict__ W6, const float* __restrict__ W7,
                     short* __restrict__ ws, float* __restrict__ out) {
  const int l = blockIdx.y;
  const int le = blockIdx.x * 256 + threadIdx.x;    // < 65536
  if (l == 1) { out[le] = 0.f; out[le + 65536] = 0.f; }
  int K, N, off; const float* W;
  switch (l) {
    case 0:  K = 512; N = 128; off = 0;      W = W0; break;
    case 1:  K = 128; N = 256; off = 65536;  W = W1; break;
    case 2:  K = 256; N = 128; off = 98304;  W = W2; break;
    case 3:  K = 128; N = 256; off = 131072; W = W3; break;
    case 4:  K = 256; N = 128; off = 163840; W = W4; break;
    case 5:  K = 128; N = 256; off = 196608; W = W5; break;
    case 6:  K = 256; N = 128; off = 229376; W = W6; break;
    default: K = 128; N = 256; off = 262144; W = W7; break;
  }
  if (le >= K * N) return;
  const int k = le / N, n = le % N;                 // coalesced read of W[k][n]
  ws[off + n * K + k] = f2bf(W[le]);
}

extern "C" void kernel_launch(void* const* d_in, const int* in_sizes, int n_in,
                              void* d_out, int out_size, void* d_ws, size_t ws_size,
                              hipStream_t stream) {
  const float* h0  = (const float*)d_in[0];
  const float* hT  = (const float*)d_in[1];
  const float* gW0 = (const float*)d_in[2];  const float* gb0 = (const float*)d_in[3];
  const float* gW1 = (const float*)d_in[4];  const float* gb1 = (const float*)d_in[5];
  const float* gW2 = (const float*)d_in[6];  const float* gb2 = (const float*)d_in[7];
  const float* gW3 = (const float*)d_in[8];  const float* gb3 = (const float*)d_in[9];
  const float* oW0 = (const float*)d_in[10]; const float* ob0 = (const float*)d_in[11];
  const float* oW1 = (const float*)d_in[12]; const float* ob1 = (const float*)d_in[13];
  const float* oW2 = (const float*)d_in[14]; const float* ob2 = (const float*)d_in[15];
  const float* oW3 = (const float*)d_in[16]; const float* ob3 = (const float*)d_in[17];
  float* out = (float*)d_out;
  short* ws  = (short*)d_ws;   // 589824 B

  prep<<<dim3(256, 8), 256, 0, stream>>>(gW0, gW1, gW2, gW3, oW0, oW1, oW2, oW3, ws, out);
  readout_main<<<NWG, 256, 0, stream>>>(h0, hT, ws,
                                        gb0, gb1, gb2, gb3,
                                        ob0, ob1, ob2, ob3, out);
}

// Round 3
// 483.314 us; speedup vs baseline: 1.2684x; 1.0775x over previous
//
#include <hip/hip_runtime.h>
#include <hip/hip_bf16.h>
#include <stdint.h>

// ---------------------------------------------------------------------------
// Round 3: 32x32x16 MFMA (2x MACs per operand byte), 64 rows/WG (weights read
// once per WG -> 1.18 GB L2), 4 waves, wave = 2 row-tiles x 2 col-tiles for
// N=256 / 2x1 for N=128. Gate kept in packed VGPRs. LDS ~52 KB -> 3 blocks/CU.
// B-fragments straight global->VGPR from W^T[n][k] bf16 (L2-hot).
// ---------------------------------------------------------------------------

typedef __attribute__((ext_vector_type(8))) short short8_t;
typedef __attribute__((ext_vector_type(16))) float f32x16;

#define ROWS 64
#define NWG  2048            // 131072 / 64 exactly

// LDS layout (bytes)
#define PE        (64 * 136)     // one stage buffer, shorts
#define OFF_P     0              // P db: 2 x [64][136] = 34816 B ; alias B2 [64][264] = 33792 B
#define OFF_A     34816          // A [64][136] = 17408 B
#define OFF_MASK  52224          // 64 floats
#define LDS_TOTAL 52480

__device__ __forceinline__ short f2bf(float f) {
  union { float f; uint32_t u; } v; v.f = f;
  uint32_t r = (v.u + 0x7FFFu + ((v.u >> 16) & 1u)) >> 16;  // RNE
  return (short)r;
}
__device__ __forceinline__ float bf2f(short b) {
  union { uint32_t u; float f; } v; v.u = ((uint32_t)(uint16_t)b) << 16;
  return v.f;
}

// ---- MFMA block: A from LDS, B straight from global (W^T[n][KTOT]) --------
// A layout: lane m=lane&31 -> act row (rt*32+m), k = base + (lane>>5)*8 + j.
// B layout (dual): lane n=lane&31 -> col, same k window. k-permutation cancels.
template <int KTOT, int KSTEPS, int CT>
__device__ __forceinline__ void gemm32(const short* actin, int Sin,
                                       const short* __restrict__ wsB, int kw0, int c0,
                                       f32x16 (&acc)[2][CT], int n32, int q32) {
#pragma unroll
  for (int ks = 0; ks < KSTEPS; ++ks) {
    const int kl = ks * 16 + q32 * 8;
    short8_t b[CT];
#pragma unroll
    for (int ct = 0; ct < CT; ++ct)
      b[ct] = *(const short8_t*)(wsB + (size_t)(c0 + ct * 32 + n32) * KTOT + kw0 + kl);
    short8_t a[2];
#pragma unroll
    for (int rt = 0; rt < 2; ++rt)
      a[rt] = *(const short8_t*)(actin + (rt * 32 + n32) * Sin + kl);
#pragma unroll
    for (int ct = 0; ct < CT; ++ct)
#pragma unroll
      for (int rt = 0; rt < 2; ++rt)
        acc[rt][ct] = __builtin_amdgcn_mfma_f32_32x32x16_bf16(a[rt], b[ct], acc[rt][ct], 0, 0, 0);
  }
}

// C/D layout (verified m74/m101): col = lane&31, row = (reg&3)+8*(reg>>2)+4*(lane>>5)
template <int CT, int ACTF>
__device__ __forceinline__ void epi32(f32x16 (&acc)[2][CT], short* actout, int Sout,
                                      const float* __restrict__ bias, int c0, int n32, int q32) {
#pragma unroll
  for (int ct = 0; ct < CT; ++ct) {
    const int c = c0 + ct * 32 + n32;
    const float bv = bias[c];
#pragma unroll
    for (int rt = 0; rt < 2; ++rt)
#pragma unroll
      for (int reg = 0; reg < 16; ++reg) {
        const int r = rt * 32 + (reg & 3) + 8 * (reg >> 2) + 4 * q32;
        float v = acc[rt][ct][reg] + bv;
        if (ACTF == 1) v = fmaxf(v, 0.f);
        actout[r * Sout + c] = f2bf(v);
      }
  }
}

template <int K, int N, int ACTF>
__device__ __forceinline__ void layer32(const short* actin, int Sin, short* actout, int Sout,
                                        const short* __restrict__ wsB,
                                        const float* __restrict__ bias,
                                        int wv, int n32, int q32) {
  constexpr int CT = N / 128;          // 1 (N=128) or 2 (N=256)
  const int c0 = wv * (N / 4);
  f32x16 acc[2][CT];
#pragma unroll
  for (int rt = 0; rt < 2; ++rt)
#pragma unroll
    for (int ct = 0; ct < CT; ++ct) acc[rt][ct] = (f32x16)(0.f);
  gemm32<K, K / 16, CT>(actin, Sin, wsB, 0, c0, acc, n32, q32);
  epi32<CT, ACTF>(acc, actout, Sout, bias, c0, n32, q32);
}

// ---- input streaming: 64 rows x 128 cols fp32 per chunk --------------------
__device__ __forceinline__ void stage_load(const float* __restrict__ src, int row0, int colbase,
                                           int tid, float4 (&v)[8]) {
  const int c4 = tid & 31, rb = tid >> 5;
#pragma unroll
  for (int it = 0; it < 8; ++it)
    v[it] = *(const float4*)(src + (size_t)(row0 + rb + it * 8) * 256 + colbase + c4 * 4);
}

// mmode: 0 none, 1 init maskacc, 2 accumulate
__device__ __forceinline__ void stage_store(short* Pb, int tid, const float4 (&v)[8],
                                            float* maskacc, int mmode) {
  const int c4 = tid & 31, rb = tid >> 5;
#pragma unroll
  for (int it = 0; it < 8; ++it) {
    const int r = rb + it * 8;
    short4 pk; pk.x = f2bf(v[it].x); pk.y = f2bf(v[it].y); pk.z = f2bf(v[it].z); pk.w = f2bf(v[it].w);
    *(short4*)(Pb + r * 136 + c4 * 4) = pk;
    if (mmode) {
      float s = v[it].x + v[it].y + v[it].z + v[it].w;
      s += __shfl_down(s, 16, 32);
      s += __shfl_down(s, 8, 32);
      s += __shfl_down(s, 4, 32);
      s += __shfl_down(s, 2, 32);
      s += __shfl_down(s, 1, 32);
      if (c4 == 0) {
        if (mmode == 1) maskacc[r] = s; else maskacc[r] += s;
      }
    }
  }
}

// Streamed first layer (N=128 out): chunks kc<splitc from src0, else src1.
template <int NCH, bool MASKA>
__device__ __forceinline__ void stream32(const float* __restrict__ src0,
                                         const float* __restrict__ src1, int splitc,
                                         const short* __restrict__ wsB,
                                         const float* __restrict__ bias,
                                         short* P, short* Aout, float* maskacc,
                                         int row0, int tid, int wv, int n32, int q32) {
  constexpr int KTOT = NCH * 128;
  f32x16 acc[2][1];
  acc[0][0] = (f32x16)(0.f); acc[1][0] = (f32x16)(0.f);
  float4 v[8];
  stage_load(src0, row0, 0, tid, v);
  stage_store(P, tid, v, maskacc, MASKA ? 1 : 0);
  __syncthreads();
#pragma unroll
  for (int kc = 0; kc < NCH; ++kc) {
    if (kc + 1 < NCH) {
      const bool lo = (kc + 1 < splitc);
      stage_load(lo ? src0 : src1, row0, (lo ? kc + 1 : kc + 1 - splitc) * 128, tid, v);
    }
    gemm32<KTOT, 8, 1>(P + (kc & 1) * PE, 136, wsB, kc * 128, wv * 32, acc, n32, q32);
    if (kc + 1 < NCH)
      stage_store(P + ((kc + 1) & 1) * PE, tid, v, maskacc, (MASKA && kc + 1 < splitc) ? 2 : 0);
    __syncthreads();
  }
  epi32<1, 1>(acc, Aout, 136, bias, wv * 32, n32, q32);
}

// g3: K=128 N=256 sigmoid -> packed bf16 gate in VGPRs (wave-local, C-layout)
__device__ __forceinline__ void gate_layer(const short* actin, const short* __restrict__ wsB,
                                           const float* __restrict__ bias,
                                           uint32_t (&gate)[2][2][8],
                                           int wv, int n32, int q32) {
  f32x16 acc[2][2];
#pragma unroll
  for (int rt = 0; rt < 2; ++rt)
#pragma unroll
    for (int ct = 0; ct < 2; ++ct) acc[rt][ct] = (f32x16)(0.f);
  gemm32<128, 8, 2>(actin, 136, wsB, 0, wv * 64, acc, n32, q32);
#pragma unroll
  for (int ct = 0; ct < 2; ++ct) {
    const float bv = bias[wv * 64 + ct * 32 + n32];
#pragma unroll
    for (int rt = 0; rt < 2; ++rt)
#pragma unroll
      for (int p = 0; p < 8; ++p) {
        const float g0 = 1.f / (1.f + __expf(-(acc[rt][ct][2 * p] + bv)));
        const float g1 = 1.f / (1.f + __expf(-(acc[rt][ct][2 * p + 1] + bv)));
        gate[rt][ct][p] = ((uint32_t)(uint16_t)f2bf(g1) << 16) | (uint32_t)(uint16_t)f2bf(g0);
      }
  }
}

// o3: K=128 N=256, fused mask*gate*val reduce over 64 rows + atomicAdd
__device__ __forceinline__ void final32(const short* actin, const short* __restrict__ wsB,
                                        const float* __restrict__ bias,
                                        const uint32_t (&gate)[2][2][8],
                                        const float* maskacc, float* __restrict__ out,
                                        int row0, int wv, int n32, int q32, int lane) {
  f32x16 acc[2][2];
#pragma unroll
  for (int rt = 0; rt < 2; ++rt)
#pragma unroll
    for (int ct = 0; ct < 2; ++ct) acc[rt][ct] = (f32x16)(0.f);
  gemm32<128, 8, 2>(actin, 136, wsB, 0, wv * 64, acc, n32, q32);

  const int b = row0 >> 8;       // 64 | 256, so one batch per WG
#pragma unroll
  for (int ct = 0; ct < 2; ++ct) {
    const int c = wv * 64 + ct * 32 + n32;
    const float bv = bias[c];
    float s = 0.f;
#pragma unroll
    for (int rt = 0; rt < 2; ++rt)
#pragma unroll
      for (int p = 0; p < 8; ++p) {
        const int r0 = rt * 32 + ((2 * p) & 3) + 8 * (p >> 1) + 4 * q32;  // reg=2p
        const float g0 = bf2f((short)(gate[rt][ct][p] & 0xFFFF));
        const float g1 = bf2f((short)(gate[rt][ct][p] >> 16));
        const float v0 = acc[rt][ct][2 * p] + bv;
        const float v1 = acc[rt][ct][2 * p + 1] + bv;
        if (maskacc[r0] > 0.f)     s += g0 * v0;
        if (maskacc[r0 + 1] > 0.f) s += g1 * v1;
      }
    s += __shfl_down(s, 32);
    if (lane < 32) atomicAdd(out + b * 256 + c, s);
  }
}

__global__ __launch_bounds__(256, 3)
void readout_main(const float* __restrict__ h0, const float* __restrict__ hT,
                  const short* __restrict__ ws,
                  const float* __restrict__ gb0, const float* __restrict__ gb1,
                  const float* __restrict__ gb2, const float* __restrict__ gb3,
                  const float* __restrict__ ob0, const float* __restrict__ ob1,
                  const float* __restrict__ ob2, const float* __restrict__ ob3,
                  float* __restrict__ out) {
  __shared__ __align__(16) char smem[LDS_TOTAL];
  short* P  = (short*)(smem + OFF_P);
  short* B2 = (short*)(smem + OFF_P);      // [64][264], aliases P (disjoint lifetimes)
  short* A  = (short*)(smem + OFF_A);      // [64][136]
  float* maskacc = (float*)(smem + OFF_MASK);

  const int tid = threadIdx.x, lane = tid & 63, wv = tid >> 6;
  const int n32 = lane & 31, q32 = lane >> 5;
  const int row0 = blockIdx.x * ROWS;
  uint32_t gate[2][2][8];

  // gate chain
  stream32<4, true>(h0, hT, 2, ws + 0, gb0, P, A, maskacc, row0, tid, wv, n32, q32);
  __syncthreads();
  layer32<128, 256, 1>(A, 136, B2, 264, ws + 65536, gb1, wv, n32, q32);
  __syncthreads();
  layer32<256, 128, 1>(B2, 264, A, 136, ws + 98304, gb2, wv, n32, q32);
  __syncthreads();
  gate_layer(A, ws + 131072, gb3, gate, wv, n32, q32);
  __syncthreads();
  // value chain (hT re-streamed, L3-warm)
  stream32<2, false>(hT, hT, 2, ws + 163840, ob0, P, A, maskacc, row0, tid, wv, n32, q32);
  __syncthreads();
  layer32<128, 256, 1>(A, 136, B2, 264, ws + 196608, ob1, wv, n32, q32);
  __syncthreads();
  layer32<256, 128, 1>(B2, 264, A, 136, ws + 229376, ob2, wv, n32, q32);
  __syncthreads();
  final32(A, ws + 262144, ob3, gate, maskacc, out, row0, wv, n32, q32, lane);
}

// ---- prep: transpose weights fp32[K][N] -> bf16 W^T[n][K]; zero out --------
__global__ void prep(const float* __restrict__ W0, const float* __restrict__ W1,
                     const float* __restrict__ W2, const float* __restrict__ W3,
                     const float* __restrict__ W4, const float* __restrict__ W5,
                     const float* __restrict__ W6, const float* __restrict__ W7,
                     short* __restrict__ ws, float* __restrict__ out) {
  const int l = blockIdx.y;
  const int le = blockIdx.x * 256 + threadIdx.x;    // < 65536
  if (l == 1) { out[le] = 0.f; out[le + 65536] = 0.f; }
  int K, N, off; const float* W;
  switch (l) {
    case 0:  K = 512; N = 128; off = 0;      W = W0; break;
    case 1:  K = 128; N = 256; off = 65536;  W = W1; break;
    case 2:  K = 256; N = 128; off = 98304;  W = W2; break;
    case 3:  K = 128; N = 256; off = 131072; W = W3; break;
    case 4:  K = 256; N = 128; off = 163840; W = W4; break;
    case 5:  K = 128; N = 256; off = 196608; W = W5; break;
    case 6:  K = 256; N = 128; off = 229376; W = W6; break;
    default: K = 128; N = 256; off = 262144; W = W7; break;
  }
  if (le >= K * N) return;
  const int k = le / N, n = le % N;                 // coalesced read of W[k][n]
  ws[off + n * K + k] = f2bf(W[le]);
}

extern "C" void kernel_launch(void* const* d_in, const int* in_sizes, int n_in,
                              void* d_out, int out_size, void* d_ws, size_t ws_size,
                              hipStream_t stream) {
  const float* h0  = (const float*)d_in[0];
  const float* hT  = (const float*)d_in[1];
  const float* gW0 = (const float*)d_in[2];  const float* gb0 = (const float*)d_in[3];
  const float* gW1 = (const float*)d_in[4];  const float* gb1 = (const float*)d_in[5];
  const float* gW2 = (const float*)d_in[6];  const float* gb2 = (const float*)d_in[7];
  const float* gW3 = (const float*)d_in[8];  const float* gb3 = (const float*)d_in[9];
  const float* oW0 = (const float*)d_in[10]; const float* ob0 = (const float*)d_in[11];
  const float* oW1 = (const float*)d_in[12]; const float* ob1 = (const float*)d_in[13];
  const float* oW2 = (const float*)d_in[14]; const float* ob2 = (const float*)d_in[15];
  const float* oW3 = (const float*)d_in[16]; const float* ob3 = (const float*)d_in[17];
  float* out = (float*)d_out;
  short* ws  = (short*)d_ws;   // 589824 B

  prep<<<dim3(256, 8), 256, 0, stream>>>(gW0, gW1, gW2, gW3, oW0, oW1, oW2, oW3, ws, out);
  readout_main<<<NWG, 256, 0, stream>>>(h0, hT, ws,
                                        gb0, gb1, gb2, gb3,
                                        ob0, ob1, ob2, ob3, out);
}

// Round 4
// 467.548 us; speedup vs baseline: 1.3112x; 1.0337x over previous
//
#include <hip/hip_runtime.h>
#include <hip/hip_bf16.h>
#include <stdint.h>

// ---------------------------------------------------------------------------
// Round 4: round-3 structure with two fixes:
//  (a) __launch_bounds__(256,2): reg cap 256 -> gate stays in VGPRs, NO spills
//      (round 3's (256,3) cap ~170 caused 27 MB of scratch spill traffic).
//  (b) fragment-ordered weights: ws[l][cb][ks][lane][8] so each B-fragment
//      load is one coalesced 16B/lane x 64-lane (1 KB) fetch, full line use.
// 32x32x16 MFMA, 64 rows/WG, 4 waves, gate packed in VGPRs, fused final reduce.
// ---------------------------------------------------------------------------

typedef __attribute__((ext_vector_type(8))) short short8_t;
typedef __attribute__((ext_vector_type(16))) float f32x16;

#define ROWS 64
#define NWG  2048            // 131072 / 64 exactly

// LDS layout (bytes)
#define PE        (64 * 136)     // one stage buffer, shorts
#define OFF_P     0              // P db: 2 x [64][136] = 34816 B ; alias B2 [64][264] = 33792 B
#define OFF_A     34816          // A [64][136] = 17408 B
#define OFF_MASK  52224          // 64 floats
#define LDS_TOTAL 52480

__device__ __forceinline__ short f2bf(float f) {
  union { float f; uint32_t u; } v; v.f = f;
  uint32_t r = (v.u + 0x7FFFu + ((v.u >> 16) & 1u)) >> 16;  // RNE
  return (short)r;
}
__device__ __forceinline__ float bf2f(short b) {
  union { uint32_t u; float f; } v; v.u = ((uint32_t)(uint16_t)b) << 16;
  return v.f;
}

// ---- MFMA block: A from LDS, B coalesced from fragment-ordered global ------
// Weight layout: elem off = ((cb*KT16 + ks)<<9) + lane*8 + j
//   maps to logical n = cb*32 + (lane&31), k = ks*16 + (lane>>5)*8 + j.
// A: lane n32 -> act row (rt*32+n32), k = ks*16 + q32*8 + j. Dual k-mapping
// matches B's, so any k-permutation cancels in the dot product.
template <int KT16, int KSTEPS, int CT>
__device__ __forceinline__ void gemm32(const short* actin, int Sin,
                                       const short* __restrict__ wsB, int ks0, int cb0,
                                       f32x16 (&acc)[2][CT], int lane) {
  const int n32 = lane & 31, q32 = lane >> 5;
#pragma unroll
  for (int ks = 0; ks < KSTEPS; ++ks) {
    const int kl = ks * 16 + q32 * 8;
    short8_t b[CT];
#pragma unroll
    for (int ct = 0; ct < CT; ++ct)
      b[ct] = *(const short8_t*)(wsB + (((cb0 + ct) * KT16 + ks0 + ks) << 9) + lane * 8);
    short8_t a[2];
#pragma unroll
    for (int rt = 0; rt < 2; ++rt)
      a[rt] = *(const short8_t*)(actin + (rt * 32 + n32) * Sin + kl);
#pragma unroll
    for (int ct = 0; ct < CT; ++ct)
#pragma unroll
      for (int rt = 0; rt < 2; ++rt)
        acc[rt][ct] = __builtin_amdgcn_mfma_f32_32x32x16_bf16(a[rt], b[ct], acc[rt][ct], 0, 0, 0);
  }
}

// C/D layout (verified m74/m101): col = lane&31, row = (reg&3)+8*(reg>>2)+4*(lane>>5)
template <int CT, int ACTF>
__device__ __forceinline__ void epi32(f32x16 (&acc)[2][CT], short* actout, int Sout,
                                      const float* __restrict__ bias, int c0, int n32, int q32) {
#pragma unroll
  for (int ct = 0; ct < CT; ++ct) {
    const int c = c0 + ct * 32 + n32;
    const float bv = bias[c];
#pragma unroll
    for (int rt = 0; rt < 2; ++rt)
#pragma unroll
      for (int reg = 0; reg < 16; ++reg) {
        const int r = rt * 32 + (reg & 3) + 8 * (reg >> 2) + 4 * q32;
        float v = acc[rt][ct][reg] + bv;
        if (ACTF == 1) v = fmaxf(v, 0.f);
        actout[r * Sout + c] = f2bf(v);
      }
  }
}

template <int K, int N, int ACTF>
__device__ __forceinline__ void layer32(const short* actin, int Sin, short* actout, int Sout,
                                        const short* __restrict__ wsB,
                                        const float* __restrict__ bias,
                                        int wv, int lane) {
  constexpr int CT = N / 128;          // 1 (N=128) or 2 (N=256)
  const int cb0 = wv * CT;
  const int n32 = lane & 31, q32 = lane >> 5;
  f32x16 acc[2][CT];
#pragma unroll
  for (int rt = 0; rt < 2; ++rt)
#pragma unroll
    for (int ct = 0; ct < CT; ++ct) acc[rt][ct] = (f32x16)(0.f);
  gemm32<K / 16, K / 16, CT>(actin, Sin, wsB, 0, cb0, acc, lane);
  epi32<CT, ACTF>(acc, actout, Sout, bias, cb0 * 32, n32, q32);
}

// ---- input streaming: 64 rows x 128 cols fp32 per chunk --------------------
__device__ __forceinline__ void stage_load(const float* __restrict__ src, int row0, int colbase,
                                           int tid, float4 (&v)[8]) {
  const int c4 = tid & 31, rb = tid >> 5;
#pragma unroll
  for (int it = 0; it < 8; ++it)
    v[it] = *(const float4*)(src + (size_t)(row0 + rb + it * 8) * 256 + colbase + c4 * 4);
}

// mmode: 0 none, 1 init maskacc, 2 accumulate
__device__ __forceinline__ void stage_store(short* Pb, int tid, const float4 (&v)[8],
                                            float* maskacc, int mmode) {
  const int c4 = tid & 31, rb = tid >> 5;
#pragma unroll
  for (int it = 0; it < 8; ++it) {
    const int r = rb + it * 8;
    short4 pk; pk.x = f2bf(v[it].x); pk.y = f2bf(v[it].y); pk.z = f2bf(v[it].z); pk.w = f2bf(v[it].w);
    *(short4*)(Pb + r * 136 + c4 * 4) = pk;
    if (mmode) {
      float s = v[it].x + v[it].y + v[it].z + v[it].w;
      s += __shfl_down(s, 16, 32);
      s += __shfl_down(s, 8, 32);
      s += __shfl_down(s, 4, 32);
      s += __shfl_down(s, 2, 32);
      s += __shfl_down(s, 1, 32);
      if (c4 == 0) {
        if (mmode == 1) maskacc[r] = s; else maskacc[r] += s;
      }
    }
  }
}

// Streamed first layer (N=128 out): chunks kc<splitc from src0, else src1.
template <int NCH, bool MASKA>
__device__ __forceinline__ void stream32(const float* __restrict__ src0,
                                         const float* __restrict__ src1, int splitc,
                                         const short* __restrict__ wsB,
                                         const float* __restrict__ bias,
                                         short* P, short* Aout, float* maskacc,
                                         int row0, int tid, int wv, int lane) {
  constexpr int KT16 = NCH * 8;
  const int n32 = lane & 31, q32 = lane >> 5;
  f32x16 acc[2][1];
  acc[0][0] = (f32x16)(0.f); acc[1][0] = (f32x16)(0.f);
  float4 v[8];
  stage_load(src0, row0, 0, tid, v);
  stage_store(P, tid, v, maskacc, MASKA ? 1 : 0);
  __syncthreads();
#pragma unroll
  for (int kc = 0; kc < NCH; ++kc) {
    if (kc + 1 < NCH) {
      const bool lo = (kc + 1 < splitc);
      stage_load(lo ? src0 : src1, row0, (lo ? kc + 1 : kc + 1 - splitc) * 128, tid, v);
    }
    gemm32<KT16, 8, 1>(P + (kc & 1) * PE, 136, wsB, kc * 8, wv, acc, lane);
    if (kc + 1 < NCH)
      stage_store(P + ((kc + 1) & 1) * PE, tid, v, maskacc, (MASKA && kc + 1 < splitc) ? 2 : 0);
    __syncthreads();
  }
  epi32<1, 1>(acc, Aout, 136, bias, wv * 32, n32, q32);
}

// g3: K=128 N=256 sigmoid -> packed bf16 gate in VGPRs (wave-local, C-layout)
__device__ __forceinline__ void gate_layer(const short* actin, const short* __restrict__ wsB,
                                           const float* __restrict__ bias,
                                           uint32_t (&gate)[2][2][8],
                                           int wv, int lane) {
  const int n32 = lane & 31;
  f32x16 acc[2][2];
#pragma unroll
  for (int rt = 0; rt < 2; ++rt)
#pragma unroll
    for (int ct = 0; ct < 2; ++ct) acc[rt][ct] = (f32x16)(0.f);
  gemm32<8, 8, 2>(actin, 136, wsB, 0, wv * 2, acc, lane);
#pragma unroll
  for (int ct = 0; ct < 2; ++ct) {
    const float bv = bias[wv * 64 + ct * 32 + n32];
#pragma unroll
    for (int rt = 0; rt < 2; ++rt)
#pragma unroll
      for (int p = 0; p < 8; ++p) {
        const float g0 = 1.f / (1.f + __expf(-(acc[rt][ct][2 * p] + bv)));
        const float g1 = 1.f / (1.f + __expf(-(acc[rt][ct][2 * p + 1] + bv)));
        gate[rt][ct][p] = ((uint32_t)(uint16_t)f2bf(g1) << 16) | (uint32_t)(uint16_t)f2bf(g0);
      }
  }
}

// o3: K=128 N=256, fused mask*gate*val reduce over 64 rows + atomicAdd
__device__ __forceinline__ void final32(const short* actin, const short* __restrict__ wsB,
                                        const float* __restrict__ bias,
                                        const uint32_t (&gate)[2][2][8],
                                        const float* maskacc, float* __restrict__ out,
                                        int row0, int wv, int lane) {
  const int n32 = lane & 31, q32 = lane >> 5;
  f32x16 acc[2][2];
#pragma unroll
  for (int rt = 0; rt < 2; ++rt)
#pragma unroll
    for (int ct = 0; ct < 2; ++ct) acc[rt][ct] = (f32x16)(0.f);
  gemm32<8, 8, 2>(actin, 136, wsB, 0, wv * 2, acc, lane);

  const int b = row0 >> 8;       // 64 | 256, one batch per WG
#pragma unroll
  for (int ct = 0; ct < 2; ++ct) {
    const int c = wv * 64 + ct * 32 + n32;
    const float bv = bias[c];
    float s = 0.f;
#pragma unroll
    for (int rt = 0; rt < 2; ++rt)
#pragma unroll
      for (int p = 0; p < 8; ++p) {
        const int r0 = rt * 32 + ((2 * p) & 3) + 8 * (p >> 1) + 4 * q32;  // reg=2p
        const float g0 = bf2f((short)(gate[rt][ct][p] & 0xFFFF));
        const float g1 = bf2f((short)(gate[rt][ct][p] >> 16));
        const float v0 = acc[rt][ct][2 * p] + bv;
        const float v1 = acc[rt][ct][2 * p + 1] + bv;
        if (maskacc[r0] > 0.f)     s += g0 * v0;
        if (maskacc[r0 + 1] > 0.f) s += g1 * v1;
      }
    s += __shfl_down(s, 32);
    if (lane < 32) atomicAdd(out + b * 256 + c, s);
  }
}

__global__ __launch_bounds__(256, 2)
void readout_main(const float* __restrict__ h0, const float* __restrict__ hT,
                  const short* __restrict__ ws,
                  const float* __restrict__ gb0, const float* __restrict__ gb1,
                  const float* __restrict__ gb2, const float* __restrict__ gb3,
                  const float* __restrict__ ob0, const float* __restrict__ ob1,
                  const float* __restrict__ ob2, const float* __restrict__ ob3,
                  float* __restrict__ out) {
  __shared__ __align__(16) char smem[LDS_TOTAL];
  short* P  = (short*)(smem + OFF_P);
  short* B2 = (short*)(smem + OFF_P);      // [64][264], aliases P (disjoint lifetimes)
  short* A  = (short*)(smem + OFF_A);      // [64][136]
  float* maskacc = (float*)(smem + OFF_MASK);

  const int tid = threadIdx.x, lane = tid & 63, wv = tid >> 6;
  const int row0 = blockIdx.x * ROWS;
  uint32_t gate[2][2][8];

  // gate chain
  stream32<4, true>(h0, hT, 2, ws + 0, gb0, P, A, maskacc, row0, tid, wv, lane);
  __syncthreads();
  layer32<128, 256, 1>(A, 136, B2, 264, ws + 65536, gb1, wv, lane);
  __syncthreads();
  layer32<256, 128, 1>(B2, 264, A, 136, ws + 98304, gb2, wv, lane);
  __syncthreads();
  gate_layer(A, ws + 131072, gb3, gate, wv, lane);
  __syncthreads();
  // value chain (hT re-streamed, L3-warm)
  stream32<2, false>(hT, hT, 2, ws + 163840, ob0, P, A, maskacc, row0, tid, wv, lane);
  __syncthreads();
  layer32<128, 256, 1>(A, 136, B2, 264, ws + 196608, ob1, wv, lane);
  __syncthreads();
  layer32<256, 128, 1>(B2, 264, A, 136, ws + 229376, ob2, wv, lane);
  __syncthreads();
  final32(A, ws + 262144, ob3, gate, maskacc, out, row0, wv, lane);
}

// ---- prep: weights fp32[K][N] -> bf16 fragment-ordered; zero out -----------
// ws elem off = layer_off + ((cb*(K/16) + ks)<<9) + lanei*8 + j
//   with n = cb*32 + (lanei&31), k = ks*16 + (lanei>>5)*8 + j.
__global__ void prep(const float* __restrict__ W0, const float* __restrict__ W1,
                     const float* __restrict__ W2, const float* __restrict__ W3,
                     const float* __restrict__ W4, const float* __restrict__ W5,
                     const float* __restrict__ W6, const float* __restrict__ W7,
                     short* __restrict__ ws, float* __restrict__ out) {
  const int l = blockIdx.y;
  const int le = blockIdx.x * 256 + threadIdx.x;    // < 65536
  if (l == 1) { out[le] = 0.f; out[le + 65536] = 0.f; }
  int K, N, off; const float* W;
  switch (l) {
    case 0:  K = 512; N = 128; off = 0;      W = W0; break;
    case 1:  K = 128; N = 256; off = 65536;  W = W1; break;
    case 2:  K = 256; N = 128; off = 98304;  W = W2; break;
    case 3:  K = 128; N = 256; off = 131072; W = W3; break;
    case 4:  K = 256; N = 128; off = 163840; W = W4; break;
    case 5:  K = 128; N = 256; off = 196608; W = W5; break;
    case 6:  K = 256; N = 128; off = 229376; W = W6; break;
    default: K = 128; N = 256; off = 262144; W = W7; break;
  }
  if (le >= K * N) return;
  const int j = le & 7;
  const int lanei = (le >> 3) & 63;
  const int blk = le >> 9;
  const int kt16 = K >> 4;
  const int ks = blk % kt16, cb = blk / kt16;
  const int n = cb * 32 + (lanei & 31);
  const int k = ks * 16 + (lanei >> 5) * 8 + j;
  ws[off + le] = f2bf(W[k * N + n]);    // coalesced write, gathered read
}

extern "C" void kernel_launch(void* const* d_in, const int* in_sizes, int n_in,
                              void* d_out, int out_size, void* d_ws, size_t ws_size,
                              hipStream_t stream) {
  const float* h0  = (const float*)d_in[0];
  const float* hT  = (const float*)d_in[1];
  const float* gW0 = (const float*)d_in[2];  const float* gb0 = (const float*)d_in[3];
  const float* gW1 = (const float*)d_in[4];  const float* gb1 = (const float*)d_in[5];
  const float* gW2 = (const float*)d_in[6];  const float* gb2 = (const float*)d_in[7];
  const float* gW3 = (const float*)d_in[8];  const float* gb3 = (const float*)d_in[9];
  const float* oW0 = (const float*)d_in[10]; const float* ob0 = (const float*)d_in[11];
  const float* oW1 = (const float*)d_in[12]; const float* ob1 = (const float*)d_in[13];
  const float* oW2 = (const float*)d_in[14]; const float* ob2 = (const float*)d_in[15];
  const float* oW3 = (const float*)d_in[16]; const float* ob3 = (const float*)d_in[17];
  float* out = (float*)d_out;
  short* ws  = (short*)d_ws;   // 589824 B

  prep<<<dim3(256, 8), 256, 0, stream>>>(gW0, gW1, gW2, gW3, oW0, oW1, oW2, oW3, ws, out);
  readout_main<<<NWG, 256, 0, stream>>>(h0, hT, ws,
                                        gb0, gb1, gb2, gb3,
                                        ob0, ob1, ob2, ob3, out);
}